// Round 8
// baseline (373.781 us; speedup 1.0000x reference)
//
#include <hip/hip_runtime.h>

// GResNet GCN: N=50000, E=800000, d=128 (out 64).
// R8 changes (post-mortem: ~33 wave-inst/edge, half of it 64-bit addr math):
//  (1) 32-bit byte-offset addressing in all aggregates (kills v_mul64 chains).
//  (2) esc2[pos]=(outnorm,innorm)[src] written in CSR order during fill ->
//      per-edge scale load becomes streaming, not random+dependent.
//  (3) DEG_BLOCKS 128 (fill_csr was using only half the CUs).

#define GN 50000
#define GE 800000
#define SCAN_CHUNK 1024
#define DEG_BLOCKS 128
#define DEG_SLICE 6250       // GE / DEG_BLOCKS
#define HALF_NODES 25000
#define HALF_WORDS 12500     // packed uint16 pairs

typedef __attribute__((ext_vector_type(8))) short bf16x8;
typedef __attribute__((ext_vector_type(4))) float f32x4;

__device__ __forceinline__ float u2f(unsigned int u) { return __uint_as_float(u); }

__device__ __forceinline__ unsigned int bfr(float a) {   // fp32 -> bf16 bits (RNE)
  unsigned int u = __float_as_uint(a);
  return (u + 0x7fffu + ((u >> 16) & 1u)) >> 16;
}
__device__ __forceinline__ unsigned int bfpack(float a, float b) {
  return bfr(a) | (bfr(b) << 16);
}
__device__ __forceinline__ void bfunpack8(uint4 u, float* f) {
  f[0] = u2f(u.x << 16); f[1] = u2f(u.x & 0xffff0000u);
  f[2] = u2f(u.y << 16); f[3] = u2f(u.y & 0xffff0000u);
  f[4] = u2f(u.z << 16); f[5] = u2f(u.z & 0xffff0000u);
  f[6] = u2f(u.w << 16); f[7] = u2f(u.w & 0xffff0000u);
}

// ---- degrees via LDS histograms ----
// blockIdx: b = bits[0:7) slice, half = bit 7, dir = bit 8 (0=dst/in, 1=src/out)
__global__ __launch_bounds__(512) void degrees_lds_kernel(
    const int* __restrict__ src, const int* __restrict__ dst,
    unsigned int* __restrict__ partials, int E) {
  __shared__ unsigned int hist[HALF_WORDS];
  for (int i = threadIdx.x; i < HALF_WORDS; i += 512) hist[i] = 0u;
  __syncthreads();
  int b    = blockIdx.x & 127;
  int half = (blockIdx.x >> 7) & 1;
  int dir  = blockIdx.x >> 8;
  const int* __restrict__ idx = dir ? src : dst;
  int lo = half * HALF_NODES, hi = lo + HALF_NODES;
  int s = b * DEG_SLICE;
  int e = min(s + DEG_SLICE, E);
  for (int i = s + threadIdx.x; i < e; i += 512) {
    int node = idx[i];
    if (node >= lo && node < hi) {
      int local = node - lo;
      atomicAdd(&hist[local >> 1], 1u << ((local & 1) << 4));
    }
  }
  __syncthreads();
  unsigned int* outp = partials + (((size_t)dir * 2 + half) * DEG_BLOCKS + b) * HALF_WORDS;
  for (int i = threadIdx.x; i < HALF_WORDS; i += 512) outp[i] = hist[i];
}

// Reduce partials -> indeg/norms (+ packed float2 norms), rel16 slice prefix.
__global__ void degrees_reduce_kernel(const unsigned int* __restrict__ partials,
                                      int* __restrict__ indeg, float* __restrict__ innorm,
                                      float* __restrict__ outnorm, float2* __restrict__ nrm2,
                                      unsigned int* __restrict__ rel16pk) {
  int g = blockIdx.x * blockDim.x + threadIdx.x;
  if (g >= 2 * HALF_WORDS) return;
  int half = (g >= HALF_WORDS) ? 1 : 0;
  int w = g - half * HALF_WORDS;
  int n0 = half * HALF_NODES + 2 * w;
  unsigned int inLo = 0, inHi = 0, outLo = 0, outHi = 0;
  const unsigned int* pIn  = partials + ((size_t)(0 * 2 + half) * DEG_BLOCKS) * HALF_WORDS + w;
  const unsigned int* pOut = partials + ((size_t)(1 * 2 + half) * DEG_BLOCKS) * HALF_WORDS + w;
#pragma unroll 4
  for (int b = 0; b < DEG_BLOCKS; b++) {
    rel16pk[((size_t)b * GN + n0) >> 1] = inLo | (inHi << 16);
    unsigned int v = pIn[(size_t)b * HALF_WORDS];
    inLo += v & 0xffffu; inHi += v >> 16;
    unsigned int u = pOut[(size_t)b * HALF_WORDS];
    outLo += u & 0xffffu; outHi += u >> 16;
  }
  indeg[n0]     = (int)inLo;
  indeg[n0 + 1] = (int)inHi;
  float i0 = rsqrtf((float)max((int)inLo, 1)),  i1 = rsqrtf((float)max((int)inHi, 1));
  float o0 = rsqrtf((float)max((int)outLo, 1)), o1 = rsqrtf((float)max((int)outHi, 1));
  innorm[n0] = i0; innorm[n0 + 1] = i1;
  outnorm[n0] = o0; outnorm[n0 + 1] = o1;
  nrm2[n0]     = make_float2(o0, i0);
  nrm2[n0 + 1] = make_float2(o1, i1);
}

// ---- hierarchical scan over indeg -> offsets ----
__global__ __launch_bounds__(256) void scan_blocksums(const int* __restrict__ deg,
                                                      int* __restrict__ bsums, int n) {
  int tid = threadIdx.x;
  int i = blockIdx.x * SCAN_CHUNK + tid * 4;
  int s = 0;
  if (i + 3 < n) {
    int4 v = *(const int4*)(deg + i);
    s = v.x + v.y + v.z + v.w;
  } else {
    for (int j = 0; j < 4; j++) if (i + j < n) s += deg[i + j];
  }
  for (int off = 32; off; off >>= 1) s += __shfl_down(s, off);
  __shared__ int ws[4];
  if ((tid & 63) == 0) ws[tid >> 6] = s;
  __syncthreads();
  if (tid == 0) bsums[blockIdx.x] = ws[0] + ws[1] + ws[2] + ws[3];
}

__global__ void scan_bsums(const int* __restrict__ bsums, int* __restrict__ bpref,
                           int nb, int* __restrict__ offsets, int n) {
  int tid = threadIdx.x;
  int v = (tid < nb) ? bsums[tid] : 0;
  int incl = v;
  for (int off = 1; off < 64; off <<= 1) {
    int t = __shfl_up(incl, off);
    if (tid >= off) incl += t;
  }
  if (tid < nb) bpref[tid] = incl - v;
  if (tid == 63) offsets[n] = incl;
}

__global__ __launch_bounds__(256) void scan_final(const int* __restrict__ deg,
                                                  const int* __restrict__ bpref,
                                                  int* __restrict__ offsets, int n) {
  int tid = threadIdx.x;
  int i = blockIdx.x * SCAN_CHUNK + tid * 4;
  int v[4];
#pragma unroll
  for (int j = 0; j < 4; j++) v[j] = (i + j < n) ? deg[i + j] : 0;
  int tsum = v[0] + v[1] + v[2] + v[3];
  int incl = tsum;
  for (int off = 1; off < 64; off <<= 1) {
    int t = __shfl_up(incl, off);
    if ((tid & 63) >= off) incl += t;
  }
  __shared__ int wsum[4];
  int wid = tid >> 6, lane = tid & 63;
  if (lane == 63) wsum[wid] = incl;
  __syncthreads();
  int wpref = 0;
  for (int w = 0; w < wid; w++) wpref += wsum[w];
  int run = bpref[blockIdx.x] + wpref + incl - tsum;
#pragma unroll
  for (int j = 0; j < 4; j++) {
    if (i + j < n) offsets[i + j] = run;
    run += v[j];
  }
}

// ---- CSR fill via LDS counting sort; also writes edge-ordered scales ----
__global__ __launch_bounds__(512) void fill_csr_lds_kernel(
    const int* __restrict__ src, const int* __restrict__ dst,
    const int* __restrict__ offsets, const unsigned short* __restrict__ rel16,
    const float2* __restrict__ nrm2, int* __restrict__ csr,
    float2* __restrict__ esc2, int E) {
  __shared__ unsigned int cnt[HALF_WORDS];
  for (int i = threadIdx.x; i < HALF_WORDS; i += 512) cnt[i] = 0u;
  __syncthreads();
  int b    = blockIdx.x & 127;
  int half = blockIdx.x >> 7;
  int lo = half * HALF_NODES, hi = lo + HALF_NODES;
  int s = b * DEG_SLICE;
  int e = min(s + DEG_SLICE, E);
  const unsigned short* relb = rel16 + (size_t)b * GN;
  for (int i = s + threadIdx.x; i < e; i += 512) {
    int d = dst[i];
    if (d >= lo && d < hi) {
      int local = d - lo;
      int sh = (local & 1) << 4;
      unsigned int old = atomicAdd(&cnt[local >> 1], 1u << sh);
      int rank = (int)((old >> sh) & 0xffffu);
      int pos = offsets[d] + (int)relb[d] + rank;
      int sv = src[i];
      csr[pos] = sv;
      esc2[pos] = nrm2[sv];
    }
  }
}

// ---- feature fp32 -> packed bf16 ----
__global__ __launch_bounds__(256) void f32_to_bf16_kernel(const float* __restrict__ in,
                                                          uint4* __restrict__ out, int n8) {
  int t = blockIdx.x * blockDim.x + threadIdx.x;
  if (t >= n8) return;
  const float4* in4 = (const float4*)in;
  float4 f0 = in4[2 * t], f1 = in4[2 * t + 1];
  uint4 o;
  o.x = bfpack(f0.x, f0.y); o.y = bfpack(f0.z, f0.w);
  o.z = bfpack(f1.x, f1.y); o.w = bfpack(f1.z, f1.w);
  out[t] = o;
}

// ---- W -> transposed bf16 hi/lo planes ----
__global__ __launch_bounds__(256) void wconvert_kernel(
    const float* __restrict__ W0, const float* __restrict__ W1,
    const float* __restrict__ W2, const float* __restrict__ W3,
    unsigned short* __restrict__ wt) {
  int e = blockIdx.x * 256 + threadIdx.x;
  if (e >= 3 * 16384 + 8192) return;
  int m, local, N;
  if (e < 49152) { m = e >> 14; local = e & 16383; N = 128; }
  else { m = 3; local = e - 49152; N = 64; }
  const float* W = (m == 0) ? W0 : (m == 1) ? W1 : (m == 2) ? W2 : W3;
  int k = local / N, n = local % N;
  float v = W[k * N + n];
  unsigned int hi = bfr(v);
  float rem = v - u2f(hi << 16);
  unsigned int lo = bfr(rem);
  size_t hibase = (m < 3) ? (size_t)m * 32768 : 98304;
  size_t lobase = hibase + ((m < 3) ? 16384 : 8192);
  wt[hibase + (size_t)n * 128 + k] = (unsigned short)hi;
  wt[lobase + (size_t)n * 128 + k] = (unsigned short)lo;
}

// ---- aggregates over packed-bf16 rows (32-bit offsets, streamed scales) ----
// D=128, bf16 out: 16 lanes/row (16B each), 4 edge slots, 2-deep.
__global__ __launch_bounds__(256) void aggregate128_bf16_kernel(
    const char* __restrict__ hqc, const float2* __restrict__ esc2,
    const float* __restrict__ wscale, const int* __restrict__ offsets,
    const int* __restrict__ csr, uint4* __restrict__ outq, int n) {
  int node = blockIdx.x * 4 + (threadIdx.x >> 6);
  if (node >= n) return;
  int lane = threadIdx.x & 63;
  unsigned cofs = (unsigned)(lane & 15) << 4;
  int p = lane >> 4;
  int s = offsets[node], e = offsets[node + 1];
  float acc[8];
#pragma unroll
  for (int j = 0; j < 8; j++) acc[j] = 0.f;
  int i = s + p;
  for (; i + 4 < e; i += 8) {
    int sn0 = csr[i], sn1 = csr[i + 4];
    float s0 = esc2[i].x, s1 = esc2[i + 4].x;
    uint4 u0 = *(const uint4*)(hqc + (((unsigned)sn0 << 8) + cofs));
    uint4 u1 = *(const uint4*)(hqc + (((unsigned)sn1 << 8) + cofs));
    float f0[8], f1[8];
    bfunpack8(u0, f0); bfunpack8(u1, f1);
#pragma unroll
    for (int j = 0; j < 8; j++) acc[j] += f0[j] * s0 + f1[j] * s1;
  }
  if (i < e) {
    int sn = csr[i];
    float sc = esc2[i].x;
    uint4 u = *(const uint4*)(hqc + (((unsigned)sn << 8) + cofs));
    float f[8]; bfunpack8(u, f);
#pragma unroll
    for (int j = 0; j < 8; j++) acc[j] += f[j] * sc;
  }
#pragma unroll
  for (int off = 32; off >= 16; off >>= 1)
#pragma unroll
    for (int j = 0; j < 8; j++) acc[j] += __shfl_down(acc[j], off);
  if (lane < 16) {
    float w = wscale[node];
    uint4 q;
    q.x = bfpack(acc[0] * w, acc[1] * w); q.y = bfpack(acc[2] * w, acc[3] * w);
    q.z = bfpack(acc[4] * w, acc[5] * w); q.w = bfpack(acc[6] * w, acc[7] * w);
    outq[(size_t)node * 16 + (lane & 15)] = q;
  }
}

// Dual: out1(bf16) = in.*agg(out.*h), out2(bf16 res) = in.*agg(in.*h).
// esc2[i] = (outnorm[src_i], innorm[src_i]) streamed in edge order.
__global__ __launch_bounds__(256) void aggregate_dual_bf16_kernel(
    const char* __restrict__ hqc, const float2* __restrict__ esc2,
    const float* __restrict__ wscale, const int* __restrict__ offsets,
    const int* __restrict__ csr, uint4* __restrict__ out1q,
    uint4* __restrict__ out2q, int n) {
  int node = blockIdx.x * 4 + (threadIdx.x >> 6);
  if (node >= n) return;
  int lane = threadIdx.x & 63;
  unsigned cofs = (unsigned)(lane & 15) << 4;
  int p = lane >> 4;
  int s = offsets[node], e = offsets[node + 1];
  float a1[8], a2[8];
#pragma unroll
  for (int j = 0; j < 8; j++) { a1[j] = 0.f; a2[j] = 0.f; }
  int i = s + p;
  for (; i + 4 < e; i += 8) {
    int sn0 = csr[i], sn1 = csr[i + 4];
    float2 g0 = esc2[i], g1 = esc2[i + 4];
    uint4 u0 = *(const uint4*)(hqc + (((unsigned)sn0 << 8) + cofs));
    uint4 u1 = *(const uint4*)(hqc + (((unsigned)sn1 << 8) + cofs));
    float f0[8], f1[8];
    bfunpack8(u0, f0); bfunpack8(u1, f1);
#pragma unroll
    for (int j = 0; j < 8; j++) {
      a1[j] += f0[j] * g0.x + f1[j] * g1.x;
      a2[j] += f0[j] * g0.y + f1[j] * g1.y;
    }
  }
  if (i < e) {
    int sn = csr[i];
    float2 g = esc2[i];
    uint4 u = *(const uint4*)(hqc + (((unsigned)sn << 8) + cofs));
    float f[8]; bfunpack8(u, f);
#pragma unroll
    for (int j = 0; j < 8; j++) { a1[j] += f[j] * g.x; a2[j] += f[j] * g.y; }
  }
#pragma unroll
  for (int off = 32; off >= 16; off >>= 1)
#pragma unroll
    for (int j = 0; j < 8; j++) {
      a1[j] += __shfl_down(a1[j], off);
      a2[j] += __shfl_down(a2[j], off);
    }
  if (lane < 16) {
    float w = wscale[node];
    uint4 q1, q2;
    q1.x = bfpack(a1[0] * w, a1[1] * w); q1.y = bfpack(a1[2] * w, a1[3] * w);
    q1.z = bfpack(a1[4] * w, a1[5] * w); q1.w = bfpack(a1[6] * w, a1[7] * w);
    q2.x = bfpack(a2[0] * w, a2[1] * w); q2.y = bfpack(a2[2] * w, a2[3] * w);
    q2.z = bfpack(a2[4] * w, a2[5] * w); q2.w = bfpack(a2[6] * w, a2[7] * w);
    out1q[(size_t)node * 16 + (lane & 15)] = q1;
    out2q[(size_t)node * 16 + (lane & 15)] = q2;
  }
}

// D=64 (final, + bias, fp32 out): rows 128B; 8 lanes/row, 8 slots, 2-deep.
__global__ __launch_bounds__(256) void aggregate64_bf16_kernel(
    const char* __restrict__ hqc, const float2* __restrict__ esc2,
    const float* __restrict__ wscale, const float* __restrict__ bias,
    const int* __restrict__ offsets, const int* __restrict__ csr,
    float* __restrict__ out, int n) {
  int node = blockIdx.x * 4 + (threadIdx.x >> 6);
  if (node >= n) return;
  int lane = threadIdx.x & 63;
  unsigned cofs = (unsigned)(lane & 7) << 4;
  int p = lane >> 3;
  int s = offsets[node], e = offsets[node + 1];
  float acc[8];
#pragma unroll
  for (int j = 0; j < 8; j++) acc[j] = 0.f;
  int i = s + p;
  for (; i + 8 < e; i += 16) {
    int sn0 = csr[i], sn1 = csr[i + 8];
    float s0 = esc2[i].x, s1 = esc2[i + 8].x;
    uint4 u0 = *(const uint4*)(hqc + (((unsigned)sn0 << 7) + cofs));
    uint4 u1 = *(const uint4*)(hqc + (((unsigned)sn1 << 7) + cofs));
    float f0[8], f1[8];
    bfunpack8(u0, f0); bfunpack8(u1, f1);
#pragma unroll
    for (int j = 0; j < 8; j++) acc[j] += f0[j] * s0 + f1[j] * s1;
  }
  if (i < e) {
    int sn = csr[i];
    float sc = esc2[i].x;
    uint4 u = *(const uint4*)(hqc + (((unsigned)sn << 7) + cofs));
    float f[8]; bfunpack8(u, f);
#pragma unroll
    for (int j = 0; j < 8; j++) acc[j] += f[j] * sc;
  }
#pragma unroll
  for (int off = 32; off >= 8; off >>= 1)
#pragma unroll
    for (int j = 0; j < 8; j++) acc[j] += __shfl_down(acc[j], off);
  if (lane < 8) {
    int c = lane;
    float w = wscale[node];
    const float4* bp = (const float4*)bias;
    float4 b0 = bp[2 * c], b1 = bp[2 * c + 1];
    float4* orow = (float4*)(out + (size_t)node * 64);
    orow[2 * c]     = make_float4(acc[0] * w + b0.x, acc[1] * w + b0.y,
                                  acc[2] * w + b0.z, acc[3] * w + b0.w);
    orow[2 * c + 1] = make_float4(acc[4] * w + b1.x, acc[5] * w + b1.y,
                                  acc[6] * w + b1.z, acc[7] * w + b1.w);
  }
}

// ---- MFMA bf16 GEMM: out = A(Mx128) @ W + [bias] + [res bf16], relu? ----
template <int NT, bool RELU, bool HAS_BIAS, bool ADD_RES>
__global__ __launch_bounds__(256) void mfma_gemm_kernel(
    const unsigned short* __restrict__ Abf, const unsigned short* __restrict__ Wth,
    const unsigned short* __restrict__ Wtl, const float* __restrict__ bias,
    const unsigned short* __restrict__ resbf, unsigned short* __restrict__ outbf, int M) {
  constexpr int DOUT = NT * 16;
  int wid = threadIdx.x >> 6, lane = threadIdx.x & 63;
  int row0 = (blockIdx.x * 4 + wid) * 32;
  int lr = lane & 15, g = lane >> 4;
  bf16x8 a[2][4];
  bf16x8 zz = {0, 0, 0, 0, 0, 0, 0, 0};
#pragma unroll
  for (int rt = 0; rt < 2; rt++) {
    int r = row0 + rt * 16 + lr;
    if (r < M) {
      const unsigned short* ap = Abf + (size_t)r * 128 + g * 8;
#pragma unroll
      for (int s = 0; s < 4; s++) a[rt][s] = *(const bf16x8*)(ap + s * 32);
    } else {
#pragma unroll
      for (int s = 0; s < 4; s++) a[rt][s] = zz;
    }
  }
#pragma unroll
  for (int ct = 0; ct < NT; ct++) {
    const unsigned short* wph = Wth + (size_t)(ct * 16 + lr) * 128 + g * 8;
    const unsigned short* wpl = Wtl + (size_t)(ct * 16 + lr) * 128 + g * 8;
    bf16x8 wh[4], wl[4];
#pragma unroll
    for (int s = 0; s < 4; s++) {
      wh[s] = *(const bf16x8*)(wph + s * 32);
      wl[s] = *(const bf16x8*)(wpl + s * 32);
    }
    f32x4 acc0 = {0.f, 0.f, 0.f, 0.f}, acc1 = {0.f, 0.f, 0.f, 0.f};
#pragma unroll
    for (int s = 0; s < 4; s++) {
      acc0 = __builtin_amdgcn_mfma_f32_16x16x32_bf16(a[0][s], wh[s], acc0, 0, 0, 0);
      acc0 = __builtin_amdgcn_mfma_f32_16x16x32_bf16(a[0][s], wl[s], acc0, 0, 0, 0);
      acc1 = __builtin_amdgcn_mfma_f32_16x16x32_bf16(a[1][s], wh[s], acc1, 0, 0, 0);
      acc1 = __builtin_amdgcn_mfma_f32_16x16x32_bf16(a[1][s], wl[s], acc1, 0, 0, 0);
    }
    int col = ct * 16 + lr;
    float bv = HAS_BIAS ? bias[col] : 0.f;
#pragma unroll
    for (int rt = 0; rt < 2; rt++) {
      f32x4 acc = rt ? acc1 : acc0;
#pragma unroll
      for (int j = 0; j < 4; j++) {
        int r = row0 + rt * 16 + g * 4 + j;
        if (r < M) {
          float v = acc[j] + bv;
          if (ADD_RES) v += u2f((unsigned int)resbf[(size_t)r * 128 + col] << 16);
          if (RELU) v = fmaxf(v, 0.f);
          outbf[(size_t)r * DOUT + col] = (unsigned short)bfr(v);
        }
      }
    }
  }
}

extern "C" void kernel_launch(void* const* d_in, const int* in_sizes, int n_in,
                              void* d_out, int out_size, void* d_ws, size_t ws_size,
                              hipStream_t stream) {
  const float* features = (const float*)d_in[0];
  const int*   src      = (const int*)d_in[1];
  const int*   dst      = (const int*)d_in[2];
  const float* W0 = (const float*)d_in[3];
  const float* b0 = (const float*)d_in[4];
  const float* W1 = (const float*)d_in[5];
  const float* b1 = (const float*)d_in[6];
  const float* W2 = (const float*)d_in[7];
  const float* b2 = (const float*)d_in[8];
  const float* W3 = (const float*)d_in[9];
  const float* b3 = (const float*)d_in[10];
  float* out = (float*)d_out;
  const int N = GN, E = GE;

  char* ws = (char*)d_ws;
  size_t off = 0;
  auto alloc = [&](size_t bytes) -> void* {
    void* p = ws + off;
    off = (off + bytes + 255) & ~(size_t)255;
    return p;
  };
  unsigned int* partials = (unsigned int*)alloc((size_t)2 * 2 * DEG_BLOCKS * HALF_WORDS * 4);
  unsigned int* rel16pk  = (unsigned int*)alloc((size_t)DEG_BLOCKS * GN * 2);
  int*   indeg   = (int*)alloc((size_t)N * 4);
  float* innorm  = (float*)alloc((size_t)N * 4);
  float* outnorm = (float*)alloc((size_t)N * 4);
  float2* nrm2   = (float2*)alloc((size_t)N * 8);
  int*   offsets = (int*)alloc((size_t)(N + 1) * 4);
  int*   csr     = (int*)alloc((size_t)E * 4);
  float2* esc2   = (float2*)alloc((size_t)E * 8);
  int*   bsums   = (int*)alloc((size_t)256 * 4);
  int*   bpref   = (int*)alloc((size_t)256 * 4);
  unsigned short* wt = (unsigned short*)alloc((size_t)114688 * 2);
  uint4* fbf = (uint4*)alloc((size_t)N * 128 * 2);                    // features bf16
  unsigned short* resbf = (unsigned short*)alloc((size_t)N * 128 * 2); // res bf16; Ybf aliases
  unsigned short* tbf = (unsigned short*)alloc((size_t)N * 128 * 2);  // t0/t1/t2
  unsigned short* hbf = (unsigned short*)alloc((size_t)N * 128 * 2);  // h0/h1/h2
  (void)ws_size; (void)in_sizes; (void)n_in; (void)out_size;

  unsigned short* Ybf = resbf;  // Y bf16 (res dead after h2 GEMM)
  const unsigned short *w0h = wt,          *w0l = wt + 16384;
  const unsigned short *w1h = wt + 32768,  *w1l = wt + 49152;
  const unsigned short *w2h = wt + 65536,  *w2l = wt + 81920;
  const unsigned short *w3h = wt + 98304,  *w3l = wt + 106496;

  // graph prep (no global atomics anywhere)
  degrees_lds_kernel<<<4 * DEG_BLOCKS, 512, 0, stream>>>(src, dst, partials, E);
  degrees_reduce_kernel<<<(2 * HALF_WORDS + 255) / 256, 256, 0, stream>>>(
      partials, indeg, innorm, outnorm, nrm2, rel16pk);

  int nb = (N + SCAN_CHUNK - 1) / SCAN_CHUNK;  // 49
  scan_blocksums<<<nb, 256, 0, stream>>>(indeg, bsums, N);
  scan_bsums<<<1, 64, 0, stream>>>(bsums, bpref, nb, offsets, N);
  scan_final<<<nb, 256, 0, stream>>>(indeg, bpref, offsets, N);

  fill_csr_lds_kernel<<<2 * DEG_BLOCKS, 512, 0, stream>>>(
      src, dst, offsets, (const unsigned short*)rel16pk, nrm2, csr, esc2, E);

  wconvert_kernel<<<(57344 + 255) / 256, 256, 0, stream>>>(W0, W1, W2, W3, wt);
  f32_to_bf16_kernel<<<(N * 128 / 8 + 255) / 256, 256, 0, stream>>>(
      features, fbf, N * 128 / 8);

  int aggGrid  = (N + 3) / 4;
  int gemmGrid = (N + 127) / 128;  // 4 waves x 32 rows per block

  // t0(bf16) = in.*agg(out.*f); res(bf16) = in.*agg(in.*f) — one gather pass
  aggregate_dual_bf16_kernel<<<aggGrid, 256, 0, stream>>>(
      (const char*)fbf, esc2, innorm, offsets, csr, (uint4*)tbf, (uint4*)resbf, N);
  // h0 = relu(t0 @ W0 + b0) -> bf16
  mfma_gemm_kernel<8, true, true, false><<<gemmGrid, 256, 0, stream>>>(
      tbf, w0h, w0l, b0, nullptr, hbf, N);
  // t1 = in .* agg(out .* h0) -> bf16
  aggregate128_bf16_kernel<<<aggGrid, 256, 0, stream>>>(
      (const char*)hbf, esc2, innorm, offsets, csr, (uint4*)tbf, N);
  // h1 = relu(t1 @ W1 + b1 + res) -> bf16
  mfma_gemm_kernel<8, true, true, true><<<gemmGrid, 256, 0, stream>>>(
      tbf, w1h, w1l, b1, resbf, hbf, N);
  // t2 = in .* agg(out .* h1) -> bf16
  aggregate128_bf16_kernel<<<aggGrid, 256, 0, stream>>>(
      (const char*)hbf, esc2, innorm, offsets, csr, (uint4*)tbf, N);
  // h2 = relu(t2 @ W2 + b2 + res) -> bf16
  mfma_gemm_kernel<8, true, true, true><<<gemmGrid, 256, 0, stream>>>(
      tbf, w2h, w2l, b2, resbf, hbf, N);
  // Y = h2 @ W3 -> bf16 (res dead; Ybf aliases it)
  mfma_gemm_kernel<4, false, false, false><<<gemmGrid, 256, 0, stream>>>(
      hbf, w3h, w3l, nullptr, nullptr, Ybf, N);
  // out = in .* agg(out .* Y) + b3
  aggregate64_bf16_kernel<<<aggGrid, 256, 0, stream>>>(
      (const char*)Ybf, esc2, innorm, b3, offsets, csr, out, N);
}

// Round 9
// 366.614 us; speedup vs baseline: 1.0196x; 1.0196x over previous
//
#include <hip/hip_runtime.h>

// GResNet GCN: N=50000, E=800000, d=128 (out 64).
// R9 changes:
//  (1) MFMA GEMM operand swap: mfma(W,A) -> lane holds 4 consecutive out-cols
//      of one row; epilogue = uint2 stores/loads (4x fewer VMEM instrs vs 2B
//      scatter). Separate hi/lo acc chains; column-split grid.y=2 (12 w/CU).
//  (2) DEG_BLOCKS back to 64 (R8's 128 doubled prep traffic for no gain).
//  (3) 17 -> 14 dispatches: merged convert kernel, scan_bsums folded into
//      scan_final, outnorm buffer dropped.

#define GN 50000
#define GE 800000
#define SCAN_CHUNK 1024
#define DEG_BLOCKS 64
#define DEG_SLICE 12500      // GE / DEG_BLOCKS
#define HALF_NODES 25000
#define HALF_WORDS 12500     // packed uint16 pairs

typedef __attribute__((ext_vector_type(8))) short bf16x8;
typedef __attribute__((ext_vector_type(4))) float f32x4;

__device__ __forceinline__ float u2f(unsigned int u) { return __uint_as_float(u); }

__device__ __forceinline__ unsigned int bfr(float a) {   // fp32 -> bf16 bits (RNE)
  unsigned int u = __float_as_uint(a);
  return (u + 0x7fffu + ((u >> 16) & 1u)) >> 16;
}
__device__ __forceinline__ unsigned int bfpack(float a, float b) {
  return bfr(a) | (bfr(b) << 16);
}
__device__ __forceinline__ void bfunpack8(uint4 u, float* f) {
  f[0] = u2f(u.x << 16); f[1] = u2f(u.x & 0xffff0000u);
  f[2] = u2f(u.y << 16); f[3] = u2f(u.y & 0xffff0000u);
  f[4] = u2f(u.z << 16); f[5] = u2f(u.z & 0xffff0000u);
  f[6] = u2f(u.w << 16); f[7] = u2f(u.w & 0xffff0000u);
}

// ---- degrees via LDS histograms ----
// blockIdx: b = bits[0:6) slice, half = bit 6, dir = bit 7 (0=dst/in, 1=src/out)
__global__ __launch_bounds__(512) void degrees_lds_kernel(
    const int* __restrict__ src, const int* __restrict__ dst,
    unsigned int* __restrict__ partials, int E) {
  __shared__ unsigned int hist[HALF_WORDS];
  for (int i = threadIdx.x; i < HALF_WORDS; i += 512) hist[i] = 0u;
  __syncthreads();
  int b    = blockIdx.x & 63;
  int half = (blockIdx.x >> 6) & 1;
  int dir  = blockIdx.x >> 7;
  const int* __restrict__ idx = dir ? src : dst;
  int lo = half * HALF_NODES, hi = lo + HALF_NODES;
  int s = b * DEG_SLICE;
  int e = min(s + DEG_SLICE, E);
  for (int i = s + threadIdx.x; i < e; i += 512) {
    int node = idx[i];
    if (node >= lo && node < hi) {
      int local = node - lo;
      atomicAdd(&hist[local >> 1], 1u << ((local & 1) << 4));
    }
  }
  __syncthreads();
  unsigned int* outp = partials + (((size_t)dir * 2 + half) * DEG_BLOCKS + b) * HALF_WORDS;
  for (int i = threadIdx.x; i < HALF_WORDS; i += 512) outp[i] = hist[i];
}

// Reduce partials -> indeg/innorm/nrm2 + per-slice prefix rel16.
__global__ void degrees_reduce_kernel(const unsigned int* __restrict__ partials,
                                      int* __restrict__ indeg, float* __restrict__ innorm,
                                      float2* __restrict__ nrm2,
                                      unsigned int* __restrict__ rel16pk) {
  int g = blockIdx.x * blockDim.x + threadIdx.x;
  if (g >= 2 * HALF_WORDS) return;
  int half = (g >= HALF_WORDS) ? 1 : 0;
  int w = g - half * HALF_WORDS;
  int n0 = half * HALF_NODES + 2 * w;
  unsigned int inLo = 0, inHi = 0, outLo = 0, outHi = 0;
  const unsigned int* pIn  = partials + ((size_t)(0 * 2 + half) * DEG_BLOCKS) * HALF_WORDS + w;
  const unsigned int* pOut = partials + ((size_t)(1 * 2 + half) * DEG_BLOCKS) * HALF_WORDS + w;
#pragma unroll 4
  for (int b = 0; b < DEG_BLOCKS; b++) {
    rel16pk[((size_t)b * GN + n0) >> 1] = inLo | (inHi << 16);
    unsigned int v = pIn[(size_t)b * HALF_WORDS];
    inLo += v & 0xffffu; inHi += v >> 16;
    unsigned int u = pOut[(size_t)b * HALF_WORDS];
    outLo += u & 0xffffu; outHi += u >> 16;
  }
  indeg[n0]     = (int)inLo;
  indeg[n0 + 1] = (int)inHi;
  float i0 = rsqrtf((float)max((int)inLo, 1)),  i1 = rsqrtf((float)max((int)inHi, 1));
  float o0 = rsqrtf((float)max((int)outLo, 1)), o1 = rsqrtf((float)max((int)outHi, 1));
  innorm[n0] = i0; innorm[n0 + 1] = i1;
  nrm2[n0]     = make_float2(o0, i0);
  nrm2[n0 + 1] = make_float2(o1, i1);
}

// ---- scan over indeg -> offsets (2 dispatches) ----
__global__ __launch_bounds__(256) void scan_blocksums(const int* __restrict__ deg,
                                                      int* __restrict__ bsums, int n) {
  int tid = threadIdx.x;
  int i = blockIdx.x * SCAN_CHUNK + tid * 4;
  int s = 0;
  if (i + 3 < n) {
    int4 v = *(const int4*)(deg + i);
    s = v.x + v.y + v.z + v.w;
  } else {
    for (int j = 0; j < 4; j++) if (i + j < n) s += deg[i + j];
  }
  for (int off = 32; off; off >>= 1) s += __shfl_down(s, off);
  __shared__ int ws[4];
  if ((tid & 63) == 0) ws[tid >> 6] = s;
  __syncthreads();
  if (tid == 0) bsums[blockIdx.x] = ws[0] + ws[1] + ws[2] + ws[3];
}

// Each block redundantly wave-scans the <=64 block sums for its own prefix.
__global__ __launch_bounds__(256) void scan_final(const int* __restrict__ deg,
                                                  const int* __restrict__ bsums, int nb,
                                                  int* __restrict__ offsets, int n) {
  __shared__ int bpref_s, total_s;
  int tid = threadIdx.x;
  if (tid < 64) {
    int v = (tid < nb) ? bsums[tid] : 0;
    int incl = v;
    for (int off = 1; off < 64; off <<= 1) {
      int t = __shfl_up(incl, off);
      if (tid >= off) incl += t;
    }
    if (tid == (int)blockIdx.x) bpref_s = incl - v;
    if (tid == nb - 1) total_s = incl;
  }
  __syncthreads();
  int i = blockIdx.x * SCAN_CHUNK + tid * 4;
  int v[4];
#pragma unroll
  for (int j = 0; j < 4; j++) v[j] = (i + j < n) ? deg[i + j] : 0;
  int tsum = v[0] + v[1] + v[2] + v[3];
  int incl = tsum;
  for (int off = 1; off < 64; off <<= 1) {
    int t = __shfl_up(incl, off);
    if ((tid & 63) >= off) incl += t;
  }
  __shared__ int wsum[4];
  int wid = tid >> 6, lane = tid & 63;
  if (lane == 63) wsum[wid] = incl;
  __syncthreads();
  int wpref = 0;
  for (int w = 0; w < wid; w++) wpref += wsum[w];
  int run = bpref_s + wpref + incl - tsum;
#pragma unroll
  for (int j = 0; j < 4; j++) {
    if (i + j < n) offsets[i + j] = run;
    run += v[j];
  }
  if (blockIdx.x == 0 && tid == 0) offsets[n] = total_s;
}

// ---- CSR fill via LDS counting sort; writes edge-ordered scales too ----
__global__ __launch_bounds__(512) void fill_csr_lds_kernel(
    const int* __restrict__ src, const int* __restrict__ dst,
    const int* __restrict__ offsets, const unsigned short* __restrict__ rel16,
    const float2* __restrict__ nrm2, int* __restrict__ csr,
    float2* __restrict__ esc2, int E) {
  __shared__ unsigned int cnt[HALF_WORDS];
  for (int i = threadIdx.x; i < HALF_WORDS; i += 512) cnt[i] = 0u;
  __syncthreads();
  int b    = blockIdx.x & 63;
  int half = blockIdx.x >> 6;
  int lo = half * HALF_NODES, hi = lo + HALF_NODES;
  int s = b * DEG_SLICE;
  int e = min(s + DEG_SLICE, E);
  const unsigned short* relb = rel16 + (size_t)b * GN;
  for (int i = s + threadIdx.x; i < e; i += 512) {
    int d = dst[i];
    if (d >= lo && d < hi) {
      int local = d - lo;
      int sh = (local & 1) << 4;
      unsigned int old = atomicAdd(&cnt[local >> 1], 1u << sh);
      int rank = (int)((old >> sh) & 0xffffu);
      int pos = offsets[d] + (int)relb[d] + rank;
      int sv = src[i];
      csr[pos] = sv;
      esc2[pos] = nrm2[sv];
    }
  }
}

// ---- merged convert: features fp32->bf16 (blocks [0,FB)) + W hi/lo (rest) ----
#define FB_BLOCKS 3125   // N*128/8 / 256
__global__ __launch_bounds__(256) void convert_kernel(
    const float* __restrict__ fin, uint4* __restrict__ fbf,
    const float* __restrict__ W0, const float* __restrict__ W1,
    const float* __restrict__ W2, const float* __restrict__ W3,
    unsigned short* __restrict__ wt) {
  if ((int)blockIdx.x < FB_BLOCKS) {
    int t = blockIdx.x * 256 + threadIdx.x;
    const float4* in4 = (const float4*)fin;
    float4 f0 = in4[2 * t], f1 = in4[2 * t + 1];
    uint4 o;
    o.x = bfpack(f0.x, f0.y); o.y = bfpack(f0.z, f0.w);
    o.z = bfpack(f1.x, f1.y); o.w = bfpack(f1.z, f1.w);
    fbf[t] = o;
    return;
  }
  int e = (blockIdx.x - FB_BLOCKS) * 256 + threadIdx.x;
  if (e >= 3 * 16384 + 8192) return;
  int m, local, N;
  if (e < 49152) { m = e >> 14; local = e & 16383; N = 128; }
  else { m = 3; local = e - 49152; N = 64; }
  const float* W = (m == 0) ? W0 : (m == 1) ? W1 : (m == 2) ? W2 : W3;
  int k = local / N, n = local % N;
  float v = W[k * N + n];
  unsigned int hi = bfr(v);
  float rem = v - u2f(hi << 16);
  unsigned int lo = bfr(rem);
  size_t hibase = (m < 3) ? (size_t)m * 32768 : 98304;
  size_t lobase = hibase + ((m < 3) ? 16384 : 8192);
  wt[hibase + (size_t)n * 128 + k] = (unsigned short)hi;
  wt[lobase + (size_t)n * 128 + k] = (unsigned short)lo;
}

// ---- aggregates over packed-bf16 rows (32-bit offsets, streamed scales) ----
__global__ __launch_bounds__(256) void aggregate128_bf16_kernel(
    const char* __restrict__ hqc, const float2* __restrict__ esc2,
    const float* __restrict__ wscale, const int* __restrict__ offsets,
    const int* __restrict__ csr, uint4* __restrict__ outq, int n) {
  int node = blockIdx.x * 4 + (threadIdx.x >> 6);
  if (node >= n) return;
  int lane = threadIdx.x & 63;
  unsigned cofs = (unsigned)(lane & 15) << 4;
  int p = lane >> 4;
  int s = offsets[node], e = offsets[node + 1];
  float acc[8];
#pragma unroll
  for (int j = 0; j < 8; j++) acc[j] = 0.f;
  int i = s + p;
  for (; i + 4 < e; i += 8) {
    int sn0 = csr[i], sn1 = csr[i + 4];
    float s0 = esc2[i].x, s1 = esc2[i + 4].x;
    uint4 u0 = *(const uint4*)(hqc + (((unsigned)sn0 << 8) + cofs));
    uint4 u1 = *(const uint4*)(hqc + (((unsigned)sn1 << 8) + cofs));
    float f0[8], f1[8];
    bfunpack8(u0, f0); bfunpack8(u1, f1);
#pragma unroll
    for (int j = 0; j < 8; j++) acc[j] += f0[j] * s0 + f1[j] * s1;
  }
  if (i < e) {
    int sn = csr[i];
    float sc = esc2[i].x;
    uint4 u = *(const uint4*)(hqc + (((unsigned)sn << 8) + cofs));
    float f[8]; bfunpack8(u, f);
#pragma unroll
    for (int j = 0; j < 8; j++) acc[j] += f[j] * sc;
  }
#pragma unroll
  for (int off = 32; off >= 16; off >>= 1)
#pragma unroll
    for (int j = 0; j < 8; j++) acc[j] += __shfl_down(acc[j], off);
  if (lane < 16) {
    float w = wscale[node];
    uint4 q;
    q.x = bfpack(acc[0] * w, acc[1] * w); q.y = bfpack(acc[2] * w, acc[3] * w);
    q.z = bfpack(acc[4] * w, acc[5] * w); q.w = bfpack(acc[6] * w, acc[7] * w);
    outq[(size_t)node * 16 + (lane & 15)] = q;
  }
}

__global__ __launch_bounds__(256) void aggregate_dual_bf16_kernel(
    const char* __restrict__ hqc, const float2* __restrict__ esc2,
    const float* __restrict__ wscale, const int* __restrict__ offsets,
    const int* __restrict__ csr, uint4* __restrict__ out1q,
    uint4* __restrict__ out2q, int n) {
  int node = blockIdx.x * 4 + (threadIdx.x >> 6);
  if (node >= n) return;
  int lane = threadIdx.x & 63;
  unsigned cofs = (unsigned)(lane & 15) << 4;
  int p = lane >> 4;
  int s = offsets[node], e = offsets[node + 1];
  float a1[8], a2[8];
#pragma unroll
  for (int j = 0; j < 8; j++) { a1[j] = 0.f; a2[j] = 0.f; }
  int i = s + p;
  for (; i + 4 < e; i += 8) {
    int sn0 = csr[i], sn1 = csr[i + 4];
    float2 g0 = esc2[i], g1 = esc2[i + 4];
    uint4 u0 = *(const uint4*)(hqc + (((unsigned)sn0 << 8) + cofs));
    uint4 u1 = *(const uint4*)(hqc + (((unsigned)sn1 << 8) + cofs));
    float f0[8], f1[8];
    bfunpack8(u0, f0); bfunpack8(u1, f1);
#pragma unroll
    for (int j = 0; j < 8; j++) {
      a1[j] += f0[j] * g0.x + f1[j] * g1.x;
      a2[j] += f0[j] * g0.y + f1[j] * g1.y;
    }
  }
  if (i < e) {
    int sn = csr[i];
    float2 g = esc2[i];
    uint4 u = *(const uint4*)(hqc + (((unsigned)sn << 8) + cofs));
    float f[8]; bfunpack8(u, f);
#pragma unroll
    for (int j = 0; j < 8; j++) { a1[j] += f[j] * g.x; a2[j] += f[j] * g.y; }
  }
#pragma unroll
  for (int off = 32; off >= 16; off >>= 1)
#pragma unroll
    for (int j = 0; j < 8; j++) {
      a1[j] += __shfl_down(a1[j], off);
      a2[j] += __shfl_down(a2[j], off);
    }
  if (lane < 16) {
    float w = wscale[node];
    uint4 q1, q2;
    q1.x = bfpack(a1[0] * w, a1[1] * w); q1.y = bfpack(a1[2] * w, a1[3] * w);
    q1.z = bfpack(a1[4] * w, a1[5] * w); q1.w = bfpack(a1[6] * w, a1[7] * w);
    q2.x = bfpack(a2[0] * w, a2[1] * w); q2.y = bfpack(a2[2] * w, a2[3] * w);
    q2.z = bfpack(a2[4] * w, a2[5] * w); q2.w = bfpack(a2[6] * w, a2[7] * w);
    out1q[(size_t)node * 16 + (lane & 15)] = q1;
    out2q[(size_t)node * 16 + (lane & 15)] = q2;
  }
}

__global__ __launch_bounds__(256) void aggregate64_bf16_kernel(
    const char* __restrict__ hqc, const float2* __restrict__ esc2,
    const float* __restrict__ wscale, const float* __restrict__ bias,
    const int* __restrict__ offsets, const int* __restrict__ csr,
    float* __restrict__ out, int n) {
  int node = blockIdx.x * 4 + (threadIdx.x >> 6);
  if (node >= n) return;
  int lane = threadIdx.x & 63;
  unsigned cofs = (unsigned)(lane & 7) << 4;
  int p = lane >> 3;
  int s = offsets[node], e = offsets[node + 1];
  float acc[8];
#pragma unroll
  for (int j = 0; j < 8; j++) acc[j] = 0.f;
  int i = s + p;
  for (; i + 8 < e; i += 16) {
    int sn0 = csr[i], sn1 = csr[i + 8];
    float s0 = esc2[i].x, s1 = esc2[i + 8].x;
    uint4 u0 = *(const uint4*)(hqc + (((unsigned)sn0 << 7) + cofs));
    uint4 u1 = *(const uint4*)(hqc + (((unsigned)sn1 << 7) + cofs));
    float f0[8], f1[8];
    bfunpack8(u0, f0); bfunpack8(u1, f1);
#pragma unroll
    for (int j = 0; j < 8; j++) acc[j] += f0[j] * s0 + f1[j] * s1;
  }
  if (i < e) {
    int sn = csr[i];
    float sc = esc2[i].x;
    uint4 u = *(const uint4*)(hqc + (((unsigned)sn << 7) + cofs));
    float f[8]; bfunpack8(u, f);
#pragma unroll
    for (int j = 0; j < 8; j++) acc[j] += f[j] * sc;
  }
#pragma unroll
  for (int off = 32; off >= 8; off >>= 1)
#pragma unroll
    for (int j = 0; j < 8; j++) acc[j] += __shfl_down(acc[j], off);
  if (lane < 8) {
    int c = lane;
    float w = wscale[node];
    const float4* bp = (const float4*)bias;
    float4 b0 = bp[2 * c], b1 = bp[2 * c + 1];
    float4* orow = (float4*)(out + (size_t)node * 64);
    orow[2 * c]     = make_float4(acc[0] * w + b0.x, acc[1] * w + b0.y,
                                  acc[2] * w + b0.z, acc[3] * w + b0.w);
    orow[2 * c + 1] = make_float4(acc[4] * w + b1.x, acc[5] * w + b1.y,
                                  acc[6] * w + b1.z, acc[7] * w + b1.w);
  }
}

// ---- MFMA bf16 GEMM, operand-swapped ----
// D = mfma(Wfrag, Afrag): lane holds node row = row0+rt*16+(lane&15),
// out cols = colbase + 4*(lane>>4) + j (4 consecutive) -> uint2 epilogue.
// Each block does 4 col-tiles (64 cols); gridDim.y covers DOUT/64.
template <int DOUT, bool RELU, bool HAS_BIAS, bool ADD_RES>
__global__ __launch_bounds__(256) void mfma_gemm_kernel(
    const unsigned short* __restrict__ Abf, const unsigned short* __restrict__ Wth,
    const unsigned short* __restrict__ Wtl, const float* __restrict__ bias,
    const unsigned short* __restrict__ resbf, unsigned short* __restrict__ outbf, int M) {
  int wid = threadIdx.x >> 6, lane = threadIdx.x & 63;
  int row0 = (blockIdx.x * 4 + wid) * 32;
  int lr = lane & 15, g = lane >> 4;
  int cb = blockIdx.y * 64;          // column base for this block
  bf16x8 a[2][4];
  bf16x8 zz = {0, 0, 0, 0, 0, 0, 0, 0};
#pragma unroll
  for (int rt = 0; rt < 2; rt++) {
    int r = row0 + rt * 16 + lr;
    if (r < M) {
      const unsigned short* ap = Abf + (size_t)r * 128 + g * 8;
#pragma unroll
      for (int s = 0; s < 4; s++) a[rt][s] = *(const bf16x8*)(ap + s * 32);
    } else {
#pragma unroll
      for (int s = 0; s < 4; s++) a[rt][s] = zz;
    }
  }
  int r0 = row0 + lr, r1 = row0 + 16 + lr;
#pragma unroll
  for (int ct = 0; ct < 4; ct++) {
    int wrow = cb + ct * 16 + lr;
    const unsigned short* wph = Wth + (size_t)wrow * 128 + g * 8;
    const unsigned short* wpl = Wtl + (size_t)wrow * 128 + g * 8;
    bf16x8 wh[4], wl[4];
#pragma unroll
    for (int s = 0; s < 4; s++) {
      wh[s] = *(const bf16x8*)(wph + s * 32);
      wl[s] = *(const bf16x8*)(wpl + s * 32);
    }
    f32x4 a0h = {0.f,0.f,0.f,0.f}, a0l = {0.f,0.f,0.f,0.f};
    f32x4 a1h = {0.f,0.f,0.f,0.f}, a1l = {0.f,0.f,0.f,0.f};
#pragma unroll
    for (int s = 0; s < 4; s++) {
      a0h = __builtin_amdgcn_mfma_f32_16x16x32_bf16(wh[s], a[0][s], a0h, 0, 0, 0);
      a0l = __builtin_amdgcn_mfma_f32_16x16x32_bf16(wl[s], a[0][s], a0l, 0, 0, 0);
      a1h = __builtin_amdgcn_mfma_f32_16x16x32_bf16(wh[s], a[1][s], a1h, 0, 0, 0);
      a1l = __builtin_amdgcn_mfma_f32_16x16x32_bf16(wl[s], a[1][s], a1l, 0, 0, 0);
    }
    int c0 = cb + ct * 16 + 4 * g;   // 4 consecutive out cols per lane
    float4 bv = make_float4(0.f, 0.f, 0.f, 0.f);
    if (HAS_BIAS) bv = *(const float4*)(bias + c0);
#pragma unroll
    for (int rt = 0; rt < 2; rt++) {
      int r = rt ? r1 : r0;
      if (r < M) {
        f32x4 ah = rt ? a1h : a0h, al = rt ? a1l : a0l;
        float v0 = ah[0] + al[0] + bv.x;
        float v1 = ah[1] + al[1] + bv.y;
        float v2 = ah[2] + al[2] + bv.z;
        float v3 = ah[3] + al[3] + bv.w;
        if (ADD_RES) {
          uint2 rr = *(const uint2*)(resbf + (size_t)r * 128 + c0);
          v0 += u2f(rr.x << 16); v1 += u2f(rr.x & 0xffff0000u);
          v2 += u2f(rr.y << 16); v3 += u2f(rr.y & 0xffff0000u);
        }
        if (RELU) {
          v0 = fmaxf(v0, 0.f); v1 = fmaxf(v1, 0.f);
          v2 = fmaxf(v2, 0.f); v3 = fmaxf(v3, 0.f);
        }
        uint2 pk;
        pk.x = bfpack(v0, v1); pk.y = bfpack(v2, v3);
        *(uint2*)(outbf + (size_t)r * DOUT + c0) = pk;
      }
    }
  }
}

extern "C" void kernel_launch(void* const* d_in, const int* in_sizes, int n_in,
                              void* d_out, int out_size, void* d_ws, size_t ws_size,
                              hipStream_t stream) {
  const float* features = (const float*)d_in[0];
  const int*   src      = (const int*)d_in[1];
  const int*   dst      = (const int*)d_in[2];
  const float* W0 = (const float*)d_in[3];
  const float* b0 = (const float*)d_in[4];
  const float* W1 = (const float*)d_in[5];
  const float* b1 = (const float*)d_in[6];
  const float* W2 = (const float*)d_in[7];
  const float* b2 = (const float*)d_in[8];
  const float* W3 = (const float*)d_in[9];
  const float* b3 = (const float*)d_in[10];
  float* out = (float*)d_out;
  const int N = GN, E = GE;

  char* ws = (char*)d_ws;
  size_t off = 0;
  auto alloc = [&](size_t bytes) -> void* {
    void* p = ws + off;
    off = (off + bytes + 255) & ~(size_t)255;
    return p;
  };
  unsigned int* partials = (unsigned int*)alloc((size_t)2 * 2 * DEG_BLOCKS * HALF_WORDS * 4);
  unsigned int* rel16pk  = (unsigned int*)alloc((size_t)DEG_BLOCKS * GN * 2);
  int*   indeg   = (int*)alloc((size_t)N * 4);
  float* innorm  = (float*)alloc((size_t)N * 4);
  float2* nrm2   = (float2*)alloc((size_t)N * 8);
  int*   offsets = (int*)alloc((size_t)(N + 1) * 4);
  int*   csr     = (int*)alloc((size_t)E * 4);
  float2* esc2   = (float2*)alloc((size_t)E * 8);
  int*   bsums   = (int*)alloc((size_t)256 * 4);
  unsigned short* wt = (unsigned short*)alloc((size_t)114688 * 2);
  uint4* fbf = (uint4*)alloc((size_t)N * 128 * 2);                     // features bf16
  unsigned short* resbf = (unsigned short*)alloc((size_t)N * 128 * 2); // res bf16; Ybf aliases
  unsigned short* tbf = (unsigned short*)alloc((size_t)N * 128 * 2);   // t0/t1/t2
  unsigned short* hbf = (unsigned short*)alloc((size_t)N * 128 * 2);   // h0/h1/h2
  (void)ws_size; (void)in_sizes; (void)n_in; (void)out_size;

  unsigned short* Ybf = resbf;  // Y bf16 (res dead after h2 GEMM)
  const unsigned short *w0h = wt,          *w0l = wt + 16384;
  const unsigned short *w1h = wt + 32768,  *w1l = wt + 49152;
  const unsigned short *w2h = wt + 65536,  *w2l = wt + 81920;
  const unsigned short *w3h = wt + 98304,  *w3l = wt + 106496;

  // graph prep (no global atomics anywhere)
  degrees_lds_kernel<<<4 * DEG_BLOCKS, 512, 0, stream>>>(src, dst, partials, E);
  degrees_reduce_kernel<<<(2 * HALF_WORDS + 255) / 256, 256, 0, stream>>>(
      partials, indeg, innorm, nrm2, rel16pk);

  int nb = (N + SCAN_CHUNK - 1) / SCAN_CHUNK;  // 49
  scan_blocksums<<<nb, 256, 0, stream>>>(indeg, bsums, N);
  scan_final<<<nb, 256, 0, stream>>>(indeg, bsums, nb, offsets, N);

  fill_csr_lds_kernel<<<2 * DEG_BLOCKS, 512, 0, stream>>>(
      src, dst, offsets, (const unsigned short*)rel16pk, nrm2, csr, esc2, E);

  convert_kernel<<<FB_BLOCKS + 224, 256, 0, stream>>>(
      features, fbf, W0, W1, W2, W3, wt);

  int aggGrid = (N + 3) / 4;
  dim3 gemmGrid2((N + 127) / 128, 2);   // DOUT=128: 2 column-halves
  dim3 gemmGrid1((N + 127) / 128, 1);   // DOUT=64

  // t0(bf16) = in.*agg(out.*f); res(bf16) = in.*agg(in.*f) — one gather pass
  aggregate_dual_bf16_kernel<<<aggGrid, 256, 0, stream>>>(
      (const char*)fbf, esc2, innorm, offsets, csr, (uint4*)tbf, (uint4*)resbf, N);
  // h0 = relu(t0 @ W0 + b0) -> bf16
  mfma_gemm_kernel<128, true, true, false><<<gemmGrid2, 256, 0, stream>>>(
      tbf, w0h, w0l, b0, nullptr, hbf, N);
  // t1 = in .* agg(out .* h0) -> bf16
  aggregate128_bf16_kernel<<<aggGrid, 256, 0, stream>>>(
      (const char*)hbf, esc2, innorm, offsets, csr, (uint4*)tbf, N);
  // h1 = relu(t1 @ W1 + b1 + res) -> bf16
  mfma_gemm_kernel<128, true, true, true><<<gemmGrid2, 256, 0, stream>>>(
      tbf, w1h, w1l, b1, resbf, hbf, N);
  // t2 = in .* agg(out .* h1) -> bf16
  aggregate128_bf16_kernel<<<aggGrid, 256, 0, stream>>>(
      (const char*)hbf, esc2, innorm, offsets, csr, (uint4*)tbf, N);
  // h2 = relu(t2 @ W2 + b2 + res) -> bf16
  mfma_gemm_kernel<128, true, true, true><<<gemmGrid2, 256, 0, stream>>>(
      tbf, w2h, w2l, b2, resbf, hbf, N);
  // Y = h2 @ W3 -> bf16 (res dead; Ybf aliases it)
  mfma_gemm_kernel<64, false, false, false><<<gemmGrid1, 256, 0, stream>>>(
      hbf, w3h, w3l, nullptr, nullptr, Ybf, N);
  // out = in .* agg(out .* Y) + b3
  aggregate64_bf16_kernel<<<aggGrid, 256, 0, stream>>>(
      (const char*)Ybf, esc2, innorm, b3, offsets, csr, out, N);
}